// Round 1
// baseline (615.570 us; speedup 1.0000x reference)
//
#include <hip/hip_runtime.h>
#include <hip/hip_bf16.h>

#define BB 8
#define NN 4096
#define HH 12
#define CC 768
#define C3 2304

typedef float  f32x4  __attribute__((ext_vector_type(4)));
typedef __bf16 bf16x8 __attribute__((ext_vector_type(8)));

// ---------------------------------------------------------------------------
// Kernel 1: unnormalized logits S[b,h,i,j] = sum_n q[n,i] * k[n,j]/||k[n]||
//           and qss[b,h,i] = sum_n q[n,i]^2   (q-norm divides out per row)
// grid (16 slices, 12 h, 8 b), 256 threads. atomicAdd into zeroed ws.
// ---------------------------------------------------------------------------
__global__ __launch_bounds__(256) void k1_logits(const float* __restrict__ x,
                                                 float* __restrict__ S,
                                                 float* __restrict__ qss) {
  const int slice = blockIdx.x, h = blockIdx.y, b = blockIdx.z;
  const int tid = threadIdx.x;
  __shared__ float qb[8][68];   // +4 pad: spread banks
  __shared__ float kb[8][68];
  __shared__ float invk[8];

  const int t8     = tid >> 5;        // token-in-group 0..7
  const int lane32 = tid & 31;
  const bool isQ   = lane32 < 16;
  const int col4   = (lane32 & 15) * 4;
  const int i0     = tid >> 4;        // 0..15  (row group)
  const int jc     = tid & 15;        // 0..15  (col float4 group)

  float acc[4][4];
#pragma unroll
  for (int r = 0; r < 4; ++r)
#pragma unroll
    for (int c = 0; c < 4; ++c) acc[r][c] = 0.f;
  float qsl[4] = {0.f, 0.f, 0.f, 0.f};

  for (int g = 0; g < 32; ++g) {
    const int n = slice * 256 + g * 8 + t8;
    const float* p = x + (size_t)(b * NN + n) * C3 + (isQ ? 0 : 768) + h * 64 + col4;
    const float4 v = *(const float4*)p;
    __syncthreads();                       // previous group's compute done
    if (isQ) *(float4*)&qb[t8][col4] = v;
    else     *(float4*)&kb[t8][col4] = v;
    __syncthreads();
    {
      const float a = kb[t8][lane32];
      const float c = kb[t8][lane32 + 32];
      float ps = a * a + c * c;
      ps += __shfl_xor(ps, 1);
      ps += __shfl_xor(ps, 2);
      ps += __shfl_xor(ps, 4);
      ps += __shfl_xor(ps, 8);
      ps += __shfl_xor(ps, 16);
      if (lane32 == 0) invk[t8] = 1.0f / fmaxf(sqrtf(ps), 1e-12f);
    }
    __syncthreads();
#pragma unroll
    for (int t = 0; t < 8; ++t) {
      const float inv = invk[t];
      float4 kv = *(const float4*)&kb[t][jc * 4];
      kv.x *= inv; kv.y *= inv; kv.z *= inv; kv.w *= inv;
#pragma unroll
      for (int r = 0; r < 4; ++r) {
        const float qv = qb[t][i0 + 16 * r];
        acc[r][0] = fmaf(qv, kv.x, acc[r][0]);
        acc[r][1] = fmaf(qv, kv.y, acc[r][1]);
        acc[r][2] = fmaf(qv, kv.z, acc[r][2]);
        acc[r][3] = fmaf(qv, kv.w, acc[r][3]);
        if (jc == 0) qsl[r] = fmaf(qv, qv, qsl[r]);
      }
    }
  }

  float* Sp = S + (size_t)(b * HH + h) * 4096;
#pragma unroll
  for (int r = 0; r < 4; ++r) {
    const int i = i0 + 16 * r;
#pragma unroll
    for (int c = 0; c < 4; ++c)
      atomicAdd(&Sp[i * 64 + jc * 4 + c], acc[r][c]);
    if (jc == 0) atomicAdd(&qss[(b * HH + h) * 64 + i], qsl[r]);
  }
}

// ---------------------------------------------------------------------------
// Kernel 2: attn[b,h,i,:] = softmax( S[i,:] / max(sqrt(qss[i]),eps) * temp[h] )
// grid (12 h, 8 b), 64 threads (thread = row i)
// ---------------------------------------------------------------------------
__global__ __launch_bounds__(64) void k2_softmax(const float* __restrict__ S,
                                                 const float* __restrict__ qss,
                                                 const float* __restrict__ temp,
                                                 float* __restrict__ attn) {
  const int h = blockIdx.x, b = blockIdx.y;
  const int i = threadIdx.x;
  const size_t bh = (size_t)(b * HH + h);
  const float rqs = 1.0f / fmaxf(sqrtf(qss[bh * 64 + i]), 1e-12f);
  const float tp  = temp[h] * rqs;
  const float* Sp = S + bh * 4096 + i * 64;
  float v[64];
  float m = -3.4e38f;
#pragma unroll
  for (int j = 0; j < 64; ++j) { v[j] = Sp[j] * tp; m = fmaxf(m, v[j]); }
  float s = 0.f;
#pragma unroll
  for (int j = 0; j < 64; ++j) { v[j] = __expf(v[j] - m); s += v[j]; }
  const float inv = 1.0f / s;
  float* Ap = attn + bh * 4096 + i * 64;
#pragma unroll
  for (int j = 0; j < 64; ++j) Ap[j] = v[j] * inv;
}

// ---------------------------------------------------------------------------
// Kernel 3: W2[b,co,h*64+j] = sum_i proj_w[co,h*64+i] * attn[b,h,i,j]  (bf16)
// grid (12 co-tiles of 64, 12 h, 8 b), 256 threads
// ---------------------------------------------------------------------------
__global__ __launch_bounds__(256) void k3_w2(const float* __restrict__ attn,
                                             const float* __restrict__ pw,
                                             __bf16* __restrict__ W2) {
  const int ct = blockIdx.x, h = blockIdx.y, b = blockIdx.z;
  const int co0 = ct * 64;
  __shared__ float pT[64][65];   // pT[i][co_l] = proj_w[co0+co_l][h*64+i]
  __shared__ float ab[64][64];   // attn[i][j]
  const int tid = threadIdx.x;
  const int r = tid >> 2, c0 = (tid & 3) * 16;
  {
    const float* pp = pw + (size_t)(co0 + r) * CC + h * 64 + c0;
    const float4 p0 = *(const float4*)(pp + 0);
    const float4 p1 = *(const float4*)(pp + 4);
    const float4 p2 = *(const float4*)(pp + 8);
    const float4 p3 = *(const float4*)(pp + 12);
    const float* ap = attn + (size_t)(b * HH + h) * 4096 + r * 64 + c0;
    const float4 a0 = *(const float4*)(ap + 0);
    const float4 a1 = *(const float4*)(ap + 4);
    const float4 a2 = *(const float4*)(ap + 8);
    const float4 a3 = *(const float4*)(ap + 12);
    pT[c0 +  0][r] = p0.x; pT[c0 +  1][r] = p0.y; pT[c0 +  2][r] = p0.z; pT[c0 +  3][r] = p0.w;
    pT[c0 +  4][r] = p1.x; pT[c0 +  5][r] = p1.y; pT[c0 +  6][r] = p1.z; pT[c0 +  7][r] = p1.w;
    pT[c0 +  8][r] = p2.x; pT[c0 +  9][r] = p2.y; pT[c0 + 10][r] = p2.z; pT[c0 + 11][r] = p2.w;
    pT[c0 + 12][r] = p3.x; pT[c0 + 13][r] = p3.y; pT[c0 + 14][r] = p3.z; pT[c0 + 15][r] = p3.w;
    *(float4*)&ab[r][c0 + 0]  = a0;
    *(float4*)&ab[r][c0 + 4]  = a1;
    *(float4*)&ab[r][c0 + 8]  = a2;
    *(float4*)&ab[r][c0 + 12] = a3;
  }
  __syncthreads();
  const int col = tid & 63, jg = tid >> 6;
  float accJ[16];
#pragma unroll
  for (int c = 0; c < 16; ++c) accJ[c] = 0.f;
#pragma unroll 4
  for (int i = 0; i < 64; ++i) {
    const float p = pT[i][col];
    const float4* a4 = (const float4*)&ab[i][jg * 16];
    const float4 A0 = a4[0], A1 = a4[1], A2 = a4[2], A3 = a4[3];
    accJ[0]  = fmaf(p, A0.x, accJ[0]);  accJ[1]  = fmaf(p, A0.y, accJ[1]);
    accJ[2]  = fmaf(p, A0.z, accJ[2]);  accJ[3]  = fmaf(p, A0.w, accJ[3]);
    accJ[4]  = fmaf(p, A1.x, accJ[4]);  accJ[5]  = fmaf(p, A1.y, accJ[5]);
    accJ[6]  = fmaf(p, A1.z, accJ[6]);  accJ[7]  = fmaf(p, A1.w, accJ[7]);
    accJ[8]  = fmaf(p, A2.x, accJ[8]);  accJ[9]  = fmaf(p, A2.y, accJ[9]);
    accJ[10] = fmaf(p, A2.z, accJ[10]); accJ[11] = fmaf(p, A2.w, accJ[11]);
    accJ[12] = fmaf(p, A3.x, accJ[12]); accJ[13] = fmaf(p, A3.y, accJ[13]);
    accJ[14] = fmaf(p, A3.z, accJ[14]); accJ[15] = fmaf(p, A3.w, accJ[15]);
  }
  bf16x8 u0, u1;
#pragma unroll
  for (int c = 0; c < 8; ++c) { u0[c] = (__bf16)accJ[c]; u1[c] = (__bf16)accJ[8 + c]; }
  __bf16* wp = W2 + ((size_t)b * CC + co0 + col) * CC + h * 64 + jg * 16;
  *(bf16x8*)(wp)     = u0;
  *(bf16x8*)(wp + 8) = u1;
}

// ---------------------------------------------------------------------------
// Kernel 4: per-batch GEMM  out[b,n,co] = sum_c' v[b,n,c'] * W2[b,co,c'] + pb[co]
// A = v slice of x (fp32 -> bf16 in staging), B = W2 (bf16), gemm_bt form.
// 128x128 block tile, 4 waves of 64x64, mfma 16x16x32 bf16, K=768 (24 steps).
// grid (32 m-tiles, 6 n-tiles, 8 b), 256 threads.
// ---------------------------------------------------------------------------
__global__ __launch_bounds__(256) void k4_gemm(const float* __restrict__ x,
                                               const __bf16* __restrict__ W2,
                                               const float* __restrict__ pb,
                                               float* __restrict__ out) {
  const int mt = blockIdx.x, nt = blockIdx.y, bz = blockIdx.z;
  const int m0 = mt * 128, co0 = nt * 128;
  __shared__ __bf16 At[128][40];  // +8 bf16 pad per row
  __shared__ __bf16 Bt[128][40];
  const int tid  = threadIdx.x;
  const int w    = tid >> 6, lane = tid & 63;
  const int wm   = w >> 1,   wn   = w & 1;
  const int fr   = lane & 15;     // fragment row index
  const int fk   = lane >> 4;     // k-group 0..3

  f32x4 acc[4][4];
#pragma unroll
  for (int tm = 0; tm < 4; ++tm)
#pragma unroll
    for (int tn = 0; tn < 4; ++tn) acc[tm][tn] = (f32x4){0.f, 0.f, 0.f, 0.f};

  const int srow = tid >> 1, shalf = tid & 1;
  const float*  Ag = x  + (size_t)(bz * NN + m0 + srow) * C3 + 1536 + shalf * 16;
  const __bf16* Bg = W2 + ((size_t)bz * CC + co0 + srow) * CC + shalf * 16;

  for (int kk = 0; kk < 24; ++kk) {
    const int kb = kk * 32;
    const float4 a0 = *(const float4*)(Ag + kb + 0);
    const float4 a1 = *(const float4*)(Ag + kb + 4);
    const float4 a2 = *(const float4*)(Ag + kb + 8);
    const float4 a3 = *(const float4*)(Ag + kb + 12);
    const float4 bv0 = *(const float4*)(Bg + kb);       // 8 bf16
    const float4 bv1 = *(const float4*)(Bg + kb + 8);   // 8 bf16
    __syncthreads();               // previous compute done before overwrite
    bf16x8 ua, ub;
    ua[0] = (__bf16)a0.x; ua[1] = (__bf16)a0.y; ua[2] = (__bf16)a0.z; ua[3] = (__bf16)a0.w;
    ua[4] = (__bf16)a1.x; ua[5] = (__bf16)a1.y; ua[6] = (__bf16)a1.z; ua[7] = (__bf16)a1.w;
    ub[0] = (__bf16)a2.x; ub[1] = (__bf16)a2.y; ub[2] = (__bf16)a2.z; ub[3] = (__bf16)a2.w;
    ub[4] = (__bf16)a3.x; ub[5] = (__bf16)a3.y; ub[6] = (__bf16)a3.z; ub[7] = (__bf16)a3.w;
    *(bf16x8*)&At[srow][shalf * 16 + 0] = ua;
    *(bf16x8*)&At[srow][shalf * 16 + 8] = ub;
    *(float4*)&Bt[srow][shalf * 16 + 0] = bv0;
    *(float4*)&Bt[srow][shalf * 16 + 8] = bv1;
    __syncthreads();
    bf16x8 afr[4], bfr[4];
#pragma unroll
    for (int tm = 0; tm < 4; ++tm)
      afr[tm] = *(const bf16x8*)&At[wm * 64 + tm * 16 + fr][fk * 8];
#pragma unroll
    for (int tn = 0; tn < 4; ++tn)
      bfr[tn] = *(const bf16x8*)&Bt[wn * 64 + tn * 16 + fr][fk * 8];
#pragma unroll
    for (int tm = 0; tm < 4; ++tm)
#pragma unroll
      for (int tn = 0; tn < 4; ++tn)
        acc[tm][tn] = __builtin_amdgcn_mfma_f32_16x16x32_bf16(afr[tm], bfr[tn],
                                                              acc[tm][tn], 0, 0, 0);
  }

  // epilogue: C/D layout col = lane&15, row = (lane>>4)*4 + reg
#pragma unroll
  for (int tn = 0; tn < 4; ++tn) {
    const int co = co0 + wn * 64 + tn * 16 + fr;
    const float bias = pb[co];
#pragma unroll
    for (int tm = 0; tm < 4; ++tm) {
#pragma unroll
      for (int rr = 0; rr < 4; ++rr) {
        const int row = m0 + wm * 64 + tm * 16 + fk * 4 + rr;
        out[(size_t)(bz * NN + row) * CC + co] = acc[tm][tn][rr] + bias;
      }
    }
  }
}

// ---------------------------------------------------------------------------
extern "C" void kernel_launch(void* const* d_in, const int* in_sizes, int n_in,
                              void* d_out, int out_size, void* d_ws, size_t ws_size,
                              hipStream_t stream) {
  const float* x    = (const float*)d_in[0];
  const float* temp = (const float*)d_in[1];
  const float* pw   = (const float*)d_in[2];
  const float* pb   = (const float*)d_in[3];
  float* out = (float*)d_out;
  char* ws = (char*)d_ws;

  // ws layout (bytes):
  //   S    @ 0        : 8*12*64*64*4 = 1,572,864
  //   qss  @ 1572864  : 8*12*64*4    = 24,576
  //   attn @ 1597440  : 1,572,864
  //   W2   @ 3170304  : 8*768*768*2  = 9,437,184   (total 12.6 MB)
  float*  S    = (float*)(ws);
  float*  qss  = (float*)(ws + 1572864);
  float*  attn = (float*)(ws + 1597440);
  __bf16* W2   = (__bf16*)(ws + 3170304);

  hipMemsetAsync(ws, 0, 1597440, stream);  // zero S + qss (atomics accumulate)

  hipLaunchKernelGGL(k1_logits,  dim3(16, 12, 8), dim3(256), 0, stream, x, S, qss);
  hipLaunchKernelGGL(k2_softmax, dim3(12, 8),     dim3(64),  0, stream, S, qss, temp, attn);
  hipLaunchKernelGGL(k3_w2,      dim3(12, 12, 8), dim3(256), 0, stream, attn, pw, W2);
  hipLaunchKernelGGL(k4_gemm,    dim3(32, 6, 8),  dim3(256), 0, stream, x, W2, pb, out);
}

// Round 2
// 615.517 us; speedup vs baseline: 1.0001x; 1.0001x over previous
//
#include <hip/hip_runtime.h>
#include <hip/hip_bf16.h>

#define BB 8
#define NN 4096
#define HH 12
#define CC 768
#define C3 2304

typedef float  f32x4  __attribute__((ext_vector_type(4)));
typedef __bf16 bf16x8 __attribute__((ext_vector_type(8)));
typedef __bf16 bf16x4 __attribute__((ext_vector_type(4)));

__device__ __forceinline__ void gload16(const void* g, void* l) {
  __builtin_amdgcn_global_load_lds((const __attribute__((address_space(1))) void*)g,
                                   (__attribute__((address_space(3))) void*)l, 16, 0, 0);
}

// ---------------------------------------------------------------------------
// Kernel 0: vb[b*N+n][c] = (bf16) x[b,n,1536+c]   (dense bf16 copy of V)
// grid 24576 x 256; thread = one float4 of v
// ---------------------------------------------------------------------------
__global__ __launch_bounds__(256) void k0_vcvt(const float* __restrict__ x,
                                               __bf16* __restrict__ vb) {
  const int idx = blockIdx.x * 256 + threadIdx.x;   // 8*4096*192 total
  const int bn = idx / 192;
  const int c4 = (idx - bn * 192) * 4;
  const float4 v = *(const float4*)(x + (size_t)bn * C3 + 1536 + c4);
  bf16x4 r;
  r[0] = (__bf16)v.x; r[1] = (__bf16)v.y; r[2] = (__bf16)v.z; r[3] = (__bf16)v.w;
  *(bf16x4*)(vb + (size_t)bn * CC + c4) = r;
}

// ---------------------------------------------------------------------------
// Kernel 1: unnormalized logits S[b,h,i,j] = sum_n q[n,i] * k[n,j]/||k[n]||
//           and qss[b,h,i] = sum_n q[n,i]^2   (q-norm divides out per row)
// ---------------------------------------------------------------------------
__global__ __launch_bounds__(256) void k1_logits(const float* __restrict__ x,
                                                 float* __restrict__ S,
                                                 float* __restrict__ qss) {
  const int slice = blockIdx.x, h = blockIdx.y, b = blockIdx.z;
  const int tid = threadIdx.x;
  __shared__ float qb[8][68];
  __shared__ float kb[8][68];
  __shared__ float invk[8];

  const int t8     = tid >> 5;
  const int lane32 = tid & 31;
  const bool isQ   = lane32 < 16;
  const int col4   = (lane32 & 15) * 4;
  const int i0     = tid >> 4;
  const int jc     = tid & 15;

  float acc[4][4];
#pragma unroll
  for (int r = 0; r < 4; ++r)
#pragma unroll
    for (int c = 0; c < 4; ++c) acc[r][c] = 0.f;
  float qsl[4] = {0.f, 0.f, 0.f, 0.f};

  for (int g = 0; g < 32; ++g) {
    const int n = slice * 256 + g * 8 + t8;
    const float* p = x + (size_t)(b * NN + n) * C3 + (isQ ? 0 : 768) + h * 64 + col4;
    const float4 v = *(const float4*)p;
    __syncthreads();
    if (isQ) *(float4*)&qb[t8][col4] = v;
    else     *(float4*)&kb[t8][col4] = v;
    __syncthreads();
    {
      const float a = kb[t8][lane32];
      const float c = kb[t8][lane32 + 32];
      float ps = a * a + c * c;
      ps += __shfl_xor(ps, 1);
      ps += __shfl_xor(ps, 2);
      ps += __shfl_xor(ps, 4);
      ps += __shfl_xor(ps, 8);
      ps += __shfl_xor(ps, 16);
      if (lane32 == 0) invk[t8] = 1.0f / fmaxf(sqrtf(ps), 1e-12f);
    }
    __syncthreads();
#pragma unroll
    for (int t = 0; t < 8; ++t) {
      const float inv = invk[t];
      float4 kv = *(const float4*)&kb[t][jc * 4];
      kv.x *= inv; kv.y *= inv; kv.z *= inv; kv.w *= inv;
#pragma unroll
      for (int r = 0; r < 4; ++r) {
        const float qv = qb[t][i0 + 16 * r];
        acc[r][0] = fmaf(qv, kv.x, acc[r][0]);
        acc[r][1] = fmaf(qv, kv.y, acc[r][1]);
        acc[r][2] = fmaf(qv, kv.z, acc[r][2]);
        acc[r][3] = fmaf(qv, kv.w, acc[r][3]);
        if (jc == 0) qsl[r] = fmaf(qv, qv, qsl[r]);
      }
    }
  }

  float* Sp = S + (size_t)(b * HH + h) * 4096;
#pragma unroll
  for (int r = 0; r < 4; ++r) {
    const int i = i0 + 16 * r;
#pragma unroll
    for (int c = 0; c < 4; ++c)
      atomicAdd(&Sp[i * 64 + jc * 4 + c], acc[r][c]);
    if (jc == 0) atomicAdd(&qss[(b * HH + h) * 64 + i], qsl[r]);
  }
}

// ---------------------------------------------------------------------------
// Kernel 2: attn[b,h,i,:] = softmax( S[i,:] / max(sqrt(qss[i]),eps) * temp[h] )
// ---------------------------------------------------------------------------
__global__ __launch_bounds__(64) void k2_softmax(const float* __restrict__ S,
                                                 const float* __restrict__ qss,
                                                 const float* __restrict__ temp,
                                                 float* __restrict__ attn) {
  const int h = blockIdx.x, b = blockIdx.y;
  const int i = threadIdx.x;
  const size_t bh = (size_t)(b * HH + h);
  const float rqs = 1.0f / fmaxf(sqrtf(qss[bh * 64 + i]), 1e-12f);
  const float tp  = temp[h] * rqs;
  const float* Sp = S + bh * 4096 + i * 64;
  float v[64];
  float m = -3.4e38f;
#pragma unroll
  for (int j = 0; j < 64; ++j) { v[j] = Sp[j] * tp; m = fmaxf(m, v[j]); }
  float s = 0.f;
#pragma unroll
  for (int j = 0; j < 64; ++j) { v[j] = __expf(v[j] - m); s += v[j]; }
  const float inv = 1.0f / s;
  float* Ap = attn + bh * 4096 + i * 64;
#pragma unroll
  for (int j = 0; j < 64; ++j) Ap[j] = v[j] * inv;
}

// ---------------------------------------------------------------------------
// Kernel 3: W2[b,co,h*64+j] = sum_i proj_w[co,h*64+i] * attn[b,h,i,j]  (bf16)
// ---------------------------------------------------------------------------
__global__ __launch_bounds__(256) void k3_w2(const float* __restrict__ attn,
                                             const float* __restrict__ pw,
                                             __bf16* __restrict__ W2) {
  const int ct = blockIdx.x, h = blockIdx.y, b = blockIdx.z;
  const int co0 = ct * 64;
  __shared__ float pT[64][65];
  __shared__ float ab[64][64];
  const int tid = threadIdx.x;
  const int r = tid >> 2, c0 = (tid & 3) * 16;
  {
    const float* pp = pw + (size_t)(co0 + r) * CC + h * 64 + c0;
    const float4 p0 = *(const float4*)(pp + 0);
    const float4 p1 = *(const float4*)(pp + 4);
    const float4 p2 = *(const float4*)(pp + 8);
    const float4 p3 = *(const float4*)(pp + 12);
    const float* ap = attn + (size_t)(b * HH + h) * 4096 + r * 64 + c0;
    const float4 a0 = *(const float4*)(ap + 0);
    const float4 a1 = *(const float4*)(ap + 4);
    const float4 a2 = *(const float4*)(ap + 8);
    const float4 a3 = *(const float4*)(ap + 12);
    pT[c0 +  0][r] = p0.x; pT[c0 +  1][r] = p0.y; pT[c0 +  2][r] = p0.z; pT[c0 +  3][r] = p0.w;
    pT[c0 +  4][r] = p1.x; pT[c0 +  5][r] = p1.y; pT[c0 +  6][r] = p1.z; pT[c0 +  7][r] = p1.w;
    pT[c0 +  8][r] = p2.x; pT[c0 +  9][r] = p2.y; pT[c0 + 10][r] = p2.z; pT[c0 + 11][r] = p2.w;
    pT[c0 + 12][r] = p3.x; pT[c0 + 13][r] = p3.y; pT[c0 + 14][r] = p3.z; pT[c0 + 15][r] = p3.w;
    *(float4*)&ab[r][c0 + 0]  = a0;
    *(float4*)&ab[r][c0 + 4]  = a1;
    *(float4*)&ab[r][c0 + 8]  = a2;
    *(float4*)&ab[r][c0 + 12] = a3;
  }
  __syncthreads();
  const int col = tid & 63, jg = tid >> 6;
  float accJ[16];
#pragma unroll
  for (int c = 0; c < 16; ++c) accJ[c] = 0.f;
#pragma unroll 4
  for (int i = 0; i < 64; ++i) {
    const float p = pT[i][col];
    const float4* a4 = (const float4*)&ab[i][jg * 16];
    const float4 A0 = a4[0], A1 = a4[1], A2 = a4[2], A3 = a4[3];
    accJ[0]  = fmaf(p, A0.x, accJ[0]);  accJ[1]  = fmaf(p, A0.y, accJ[1]);
    accJ[2]  = fmaf(p, A0.z, accJ[2]);  accJ[3]  = fmaf(p, A0.w, accJ[3]);
    accJ[4]  = fmaf(p, A1.x, accJ[4]);  accJ[5]  = fmaf(p, A1.y, accJ[5]);
    accJ[6]  = fmaf(p, A1.z, accJ[6]);  accJ[7]  = fmaf(p, A1.w, accJ[7]);
    accJ[8]  = fmaf(p, A2.x, accJ[8]);  accJ[9]  = fmaf(p, A2.y, accJ[9]);
    accJ[10] = fmaf(p, A2.z, accJ[10]); accJ[11] = fmaf(p, A2.w, accJ[11]);
    accJ[12] = fmaf(p, A3.x, accJ[12]); accJ[13] = fmaf(p, A3.y, accJ[13]);
    accJ[14] = fmaf(p, A3.z, accJ[14]); accJ[15] = fmaf(p, A3.w, accJ[15]);
  }
  bf16x8 u0, u1;
#pragma unroll
  for (int c = 0; c < 8; ++c) { u0[c] = (__bf16)accJ[c]; u1[c] = (__bf16)accJ[8 + c]; }
  __bf16* wp = W2 + ((size_t)b * CC + co0 + col) * CC + h * 64 + jg * 16;
  *(bf16x8*)(wp)     = u0;
  *(bf16x8*)(wp + 8) = u1;
}

// ---------------------------------------------------------------------------
// Kernel 4: per-batch GEMM  out[b,n,co] = sum_c' vb[b,n,c'] * W2[b,co,c'] + pb[co]
// m97 recipe: 128x128 tile, BK=32, global_load_lds width 16, unpadded LDS,
// 4 waves of 64x64 (4x4 of mfma 16x16x32 bf16). XCD-aware 1-D swizzle:
// idx&7 = m-tile-in-group (stride-8 == XCD round-robin keeps A tile in one
// XCD's L2 across all 6 n-tiles), idx>>3 = n-tile.
// ---------------------------------------------------------------------------
__global__ __launch_bounds__(256) void k4_gemm(const __bf16* __restrict__ vb,
                                               const __bf16* __restrict__ W2,
                                               const float* __restrict__ pb,
                                               float* __restrict__ out) {
  int id = blockIdx.x;
  const int bz = id / 192;
  const int rem = id - bz * 192;
  const int mg = rem / 48;           // 4 m-groups of 8
  const int idx = rem - mg * 48;
  const int nt = idx >> 3;           // 0..5
  const int mt = mg * 8 + (idx & 7); // 0..31
  const int m0 = mt * 128, co0 = nt * 128;

  __shared__ __bf16 At[128][32];     // unpadded: required by global_load_lds
  __shared__ __bf16 Bt[128][32];

  const int tid  = threadIdx.x;
  const int w    = tid >> 6, lane = tid & 63;
  const int wm   = w >> 1,   wn   = w & 1;
  const int fr   = lane & 15;
  const int fk   = lane >> 4;

  f32x4 acc[4][4];
#pragma unroll
  for (int tm = 0; tm < 4; ++tm)
#pragma unroll
    for (int tn = 0; tn < 4; ++tn) acc[tm][tn] = (f32x4){0.f, 0.f, 0.f, 0.f};

  // staging: wave w covers rows [w*32, w*32+32) of each tile; lane i -> 16 B
  const int srow = lane >> 2;          // 0..15
  const int scol = (lane & 3) * 8;     // bf16 elements
  const __bf16* Ag = vb + (size_t)(bz * NN + m0 + w * 32 + srow) * CC + scol;
  const __bf16* Bg = W2 + ((size_t)bz * CC + co0 + w * 32 + srow) * CC + scol;
  __bf16* lA0 = &At[w * 32][0];
  __bf16* lA1 = &At[w * 32 + 16][0];
  __bf16* lB0 = &Bt[w * 32][0];
  __bf16* lB1 = &Bt[w * 32 + 16][0];

  for (int kk = 0; kk < 24; ++kk) {
    const int kb = kk * 32;
    __syncthreads();                 // previous tile fully consumed
    gload16(Ag + kb,            lA0);
    gload16(Ag + 16 * CC + kb,  lA1);
    gload16(Bg + kb,            lB0);
    gload16(Bg + 16 * CC + kb,  lB1);
    __syncthreads();                 // staging visible
    bf16x8 afr[4], bfr[4];
#pragma unroll
    for (int tm = 0; tm < 4; ++tm)
      afr[tm] = *(const bf16x8*)&At[wm * 64 + tm * 16 + fr][fk * 8];
#pragma unroll
    for (int tn = 0; tn < 4; ++tn)
      bfr[tn] = *(const bf16x8*)&Bt[wn * 64 + tn * 16 + fr][fk * 8];
#pragma unroll
    for (int tm = 0; tm < 4; ++tm)
#pragma unroll
      for (int tn = 0; tn < 4; ++tn)
        acc[tm][tn] = __builtin_amdgcn_mfma_f32_16x16x32_bf16(afr[tm], bfr[tn],
                                                              acc[tm][tn], 0, 0, 0);
  }

  // epilogue: C/D layout col = lane&15, row = (lane>>4)*4 + reg
#pragma unroll
  for (int tn = 0; tn < 4; ++tn) {
    const int co = co0 + wn * 64 + tn * 16 + fr;
    const float bias = pb[co];
#pragma unroll
    for (int tm = 0; tm < 4; ++tm) {
#pragma unroll
      for (int rr = 0; rr < 4; ++rr) {
        const int row = m0 + wm * 64 + tm * 16 + fk * 4 + rr;
        out[(size_t)(bz * NN + row) * CC + co] = acc[tm][tn][rr] + bias;
      }
    }
  }
}

// ---------------------------------------------------------------------------
extern "C" void kernel_launch(void* const* d_in, const int* in_sizes, int n_in,
                              void* d_out, int out_size, void* d_ws, size_t ws_size,
                              hipStream_t stream) {
  const float* x    = (const float*)d_in[0];
  const float* temp = (const float*)d_in[1];
  const float* pw   = (const float*)d_in[2];
  const float* pb   = (const float*)d_in[3];
  float* out = (float*)d_out;
  char* ws = (char*)d_ws;

  // ws layout (bytes):
  //   S    @ 0        : 8*12*64*64*4 = 1,572,864
  //   qss  @ 1572864  : 8*12*64*4    = 24,576
  //   attn @ 1597440  : 1,572,864
  //   W2   @ 3170304  : 8*768*768*2  = 9,437,184
  //   vb   @ 12607488 : 8*4096*768*2 = 50,331,648   (total ~63 MB)
  float*  S    = (float*)(ws);
  float*  qss  = (float*)(ws + 1572864);
  float*  attn = (float*)(ws + 1597440);
  __bf16* W2   = (__bf16*)(ws + 3170304);
  __bf16* vb   = (__bf16*)(ws + 12607488);

  hipMemsetAsync(ws, 0, 1597440, stream);  // zero S + qss (atomics accumulate)

  hipLaunchKernelGGL(k0_vcvt,    dim3(24576),     dim3(256), 0, stream, x, vb);
  hipLaunchKernelGGL(k1_logits,  dim3(16, 12, 8), dim3(256), 0, stream, x, S, qss);
  hipLaunchKernelGGL(k2_softmax, dim3(12, 8),     dim3(64),  0, stream, S, qss, temp, attn);
  hipLaunchKernelGGL(k3_w2,      dim3(12, 12, 8), dim3(256), 0, stream, attn, pw, W2);
  hipLaunchKernelGGL(k4_gemm,    dim3(1536),      dim3(256), 0, stream, vb, W2, pb, out);
}

// Round 3
// 534.441 us; speedup vs baseline: 1.1518x; 1.1517x over previous
//
#include <hip/hip_runtime.h>
#include <hip/hip_bf16.h>

#define BB 8
#define NN 4096
#define HH 12
#define CC 768
#define C3 2304

typedef float  f32x4  __attribute__((ext_vector_type(4)));
typedef __bf16 bf16x8 __attribute__((ext_vector_type(8)));
typedef __bf16 bf16x4 __attribute__((ext_vector_type(4)));

__device__ __forceinline__ void gload16(const void* g, void* l) {
  __builtin_amdgcn_global_load_lds((const __attribute__((address_space(1))) void*)g,
                                   (__attribute__((address_space(3))) void*)l, 16, 0, 0);
}

// ---------------------------------------------------------------------------
// Kernel 0: vb[b*N+n][c] = (bf16) x[b,n,1536+c]   (dense bf16 copy of V)
// ---------------------------------------------------------------------------
__global__ __launch_bounds__(256) void k0_vcvt(const float* __restrict__ x,
                                               __bf16* __restrict__ vb) {
  const int idx = blockIdx.x * 256 + threadIdx.x;
  const int bn = idx / 192;
  const int c4 = (idx - bn * 192) * 4;
  const float4 v = *(const float4*)(x + (size_t)bn * C3 + 1536 + c4);
  bf16x4 r;
  r[0] = (__bf16)v.x; r[1] = (__bf16)v.y; r[2] = (__bf16)v.z; r[3] = (__bf16)v.w;
  *(bf16x4*)(vb + (size_t)bn * CC + c4) = r;
}

// ---------------------------------------------------------------------------
// Kernel 1 (MFMA rewrite): per (b,h,slice of 512 tokens):
//   Spart[s,bh,i,j] = sum_n q[n,i] * k[n,j]/||k[n]||   (bf16 MFMA, fp32 acc)
//   Qpart[s,bh,i]   = sum_n q[n,i]^2                   (fp32)
// block 256 thr (4 waves); per 32-token step: stage qT/kT [64 chan][32 tok]
// bf16 transposed tiles, 16 mfma_f32_16x16x32_bf16 (wave w = 16-row strip).
// Deterministic slice partials — no atomics, no memset needed.
// ---------------------------------------------------------------------------
__global__ __launch_bounds__(256) void k1_logits(const float* __restrict__ x,
                                                 float* __restrict__ Spart,
                                                 float* __restrict__ Qpart) {
  const int slice = blockIdx.x;        // 0..7
  const int h = blockIdx.y, b = blockIdx.z;
  const int tid = threadIdx.x;
  __shared__ __bf16 qT[64][40];        // [chan][token], +8 pad (16B-aligned frags)
  __shared__ __bf16 kT[64][40];
  __shared__ float  qws[4][64];

  const int t   = tid >> 3;            // token-in-step 0..31
  const int sub = tid & 7;             // chan-group (8 chans)
  const int w   = tid >> 6, lane = tid & 63;
  const int fr  = lane & 15, fk = lane >> 4;

  const float* qbase = x + (size_t)(b * NN + slice * 512) * C3 + h * 64 + sub * 8;

  float qss8[8];
#pragma unroll
  for (int j = 0; j < 8; ++j) qss8[j] = 0.f;
  f32x4 acc[4];
#pragma unroll
  for (int tn = 0; tn < 4; ++tn) acc[tn] = (f32x4){0.f, 0.f, 0.f, 0.f};

  for (int step = 0; step < 16; ++step) {
    const float* qp = qbase + (size_t)(step * 32 + t) * C3;
    const float4 q0 = *(const float4*)(qp);
    const float4 q1 = *(const float4*)(qp + 4);
    const float4 k0 = *(const float4*)(qp + 768);
    const float4 k1 = *(const float4*)(qp + 772);
    // ||k|| over 64 chans: 8 per lane, then xor-reduce over the 8 sub-lanes
    float ss = k0.x * k0.x + k0.y * k0.y + k0.z * k0.z + k0.w * k0.w +
               k1.x * k1.x + k1.y * k1.y + k1.z * k1.z + k1.w * k1.w;
    ss += __shfl_xor(ss, 1);
    ss += __shfl_xor(ss, 2);
    ss += __shfl_xor(ss, 4);
    const float inv = 1.0f / fmaxf(sqrtf(ss), 1e-12f);
    __syncthreads();                  // previous step's frag reads complete
    const int c0 = sub * 8;
    qT[c0 + 0][t] = (__bf16)q0.x; qT[c0 + 1][t] = (__bf16)q0.y;
    qT[c0 + 2][t] = (__bf16)q0.z; qT[c0 + 3][t] = (__bf16)q0.w;
    qT[c0 + 4][t] = (__bf16)q1.x; qT[c0 + 5][t] = (__bf16)q1.y;
    qT[c0 + 6][t] = (__bf16)q1.z; qT[c0 + 7][t] = (__bf16)q1.w;
    kT[c0 + 0][t] = (__bf16)(k0.x * inv); kT[c0 + 1][t] = (__bf16)(k0.y * inv);
    kT[c0 + 2][t] = (__bf16)(k0.z * inv); kT[c0 + 3][t] = (__bf16)(k0.w * inv);
    kT[c0 + 4][t] = (__bf16)(k1.x * inv); kT[c0 + 5][t] = (__bf16)(k1.y * inv);
    kT[c0 + 6][t] = (__bf16)(k1.z * inv); kT[c0 + 7][t] = (__bf16)(k1.w * inv);
    qss8[0] = fmaf(q0.x, q0.x, qss8[0]); qss8[1] = fmaf(q0.y, q0.y, qss8[1]);
    qss8[2] = fmaf(q0.z, q0.z, qss8[2]); qss8[3] = fmaf(q0.w, q0.w, qss8[3]);
    qss8[4] = fmaf(q1.x, q1.x, qss8[4]); qss8[5] = fmaf(q1.y, q1.y, qss8[5]);
    qss8[6] = fmaf(q1.z, q1.z, qss8[6]); qss8[7] = fmaf(q1.w, q1.w, qss8[7]);
    __syncthreads();                  // staging visible
    const bf16x8 afr = *(const bf16x8*)&qT[w * 16 + fr][fk * 8];
#pragma unroll
    for (int tn = 0; tn < 4; ++tn) {
      const bf16x8 bfr = *(const bf16x8*)&kT[tn * 16 + fr][fk * 8];
      acc[tn] = __builtin_amdgcn_mfma_f32_16x16x32_bf16(afr, bfr, acc[tn], 0, 0, 0);
    }
  }

  // S partial store: C/D layout col=lane&15, row=(lane>>4)*4+reg
  const int bh = b * HH + h;
  float* Sp = Spart + ((size_t)(slice * 96 + bh)) * 4096;
#pragma unroll
  for (int tn = 0; tn < 4; ++tn)
#pragma unroll
    for (int rr = 0; rr < 4; ++rr)
      Sp[(w * 16 + fk * 4 + rr) * 64 + tn * 16 + fr] = acc[tn][rr];

  // qss: reduce over the wave's 8 tokens (lane bits 3..5), then across waves
#pragma unroll
  for (int j = 0; j < 8; ++j) {
    float v = qss8[j];
    v += __shfl_xor(v, 8);
    v += __shfl_xor(v, 16);
    v += __shfl_xor(v, 32);
    if (lane < 8) qws[w][lane * 8 + j] = v;
  }
  __syncthreads();
  if (tid < 64) {
    const float qs = qws[0][tid] + qws[1][tid] + qws[2][tid] + qws[3][tid];
    Qpart[((size_t)(slice * 96 + bh)) * 64 + tid] = qs;
  }
}

// ---------------------------------------------------------------------------
// Kernel 2: sum 8 slice-partials, then row softmax with q-norm + temperature
// ---------------------------------------------------------------------------
__global__ __launch_bounds__(64) void k2_softmax(const float* __restrict__ Spart,
                                                 const float* __restrict__ Qpart,
                                                 const float* __restrict__ temp,
                                                 float* __restrict__ attn) {
  const int h = blockIdx.x, b = blockIdx.y;
  const int i = threadIdx.x;
  const int bh = b * HH + h;
  float qs = 0.f;
#pragma unroll
  for (int s = 0; s < 8; ++s) qs += Qpart[((size_t)(s * 96 + bh)) * 64 + i];
  float v[64];
#pragma unroll
  for (int j = 0; j < 64; ++j) v[j] = 0.f;
  for (int s = 0; s < 8; ++s) {
    const float* Sp = Spart + ((size_t)(s * 96 + bh)) * 4096 + i * 64;
#pragma unroll
    for (int j = 0; j < 64; j += 4) {
      const float4 t4 = *(const float4*)(Sp + j);
      v[j] += t4.x; v[j + 1] += t4.y; v[j + 2] += t4.z; v[j + 3] += t4.w;
    }
  }
  const float rqs = 1.0f / fmaxf(sqrtf(qs), 1e-12f);
  const float tp  = temp[h] * rqs;
  float m = -3.4e38f;
#pragma unroll
  for (int j = 0; j < 64; ++j) { v[j] *= tp; m = fmaxf(m, v[j]); }
  float s = 0.f;
#pragma unroll
  for (int j = 0; j < 64; ++j) { v[j] = __expf(v[j] - m); s += v[j]; }
  const float inv = 1.0f / s;
  float* Ap = attn + (size_t)bh * 4096 + i * 64;
#pragma unroll
  for (int j = 0; j < 64; ++j) Ap[j] = v[j] * inv;
}

// ---------------------------------------------------------------------------
// Kernel 3: W2[b,co,h*64+j] = sum_i proj_w[co,h*64+i] * attn[b,h,i,j]  (bf16)
// ---------------------------------------------------------------------------
__global__ __launch_bounds__(256) void k3_w2(const float* __restrict__ attn,
                                             const float* __restrict__ pw,
                                             __bf16* __restrict__ W2) {
  const int ct = blockIdx.x, h = blockIdx.y, b = blockIdx.z;
  const int co0 = ct * 64;
  __shared__ float pT[64][65];
  __shared__ float ab[64][64];
  const int tid = threadIdx.x;
  const int r = tid >> 2, c0 = (tid & 3) * 16;
  {
    const float* pp = pw + (size_t)(co0 + r) * CC + h * 64 + c0;
    const float4 p0 = *(const float4*)(pp + 0);
    const float4 p1 = *(const float4*)(pp + 4);
    const float4 p2 = *(const float4*)(pp + 8);
    const float4 p3 = *(const float4*)(pp + 12);
    const float* ap = attn + (size_t)(b * HH + h) * 4096 + r * 64 + c0;
    const float4 a0 = *(const float4*)(ap + 0);
    const float4 a1 = *(const float4*)(ap + 4);
    const float4 a2 = *(const float4*)(ap + 8);
    const float4 a3 = *(const float4*)(ap + 12);
    pT[c0 +  0][r] = p0.x; pT[c0 +  1][r] = p0.y; pT[c0 +  2][r] = p0.z; pT[c0 +  3][r] = p0.w;
    pT[c0 +  4][r] = p1.x; pT[c0 +  5][r] = p1.y; pT[c0 +  6][r] = p1.z; pT[c0 +  7][r] = p1.w;
    pT[c0 +  8][r] = p2.x; pT[c0 +  9][r] = p2.y; pT[c0 + 10][r] = p2.z; pT[c0 + 11][r] = p2.w;
    pT[c0 + 12][r] = p3.x; pT[c0 + 13][r] = p3.y; pT[c0 + 14][r] = p3.z; pT[c0 + 15][r] = p3.w;
    *(float4*)&ab[r][c0 + 0]  = a0;
    *(float4*)&ab[r][c0 + 4]  = a1;
    *(float4*)&ab[r][c0 + 8]  = a2;
    *(float4*)&ab[r][c0 + 12] = a3;
  }
  __syncthreads();
  const int col = tid & 63, jg = tid >> 6;
  float accJ[16];
#pragma unroll
  for (int c = 0; c < 16; ++c) accJ[c] = 0.f;
#pragma unroll 4
  for (int i = 0; i < 64; ++i) {
    const float p = pT[i][col];
    const float4* a4 = (const float4*)&ab[i][jg * 16];
    const float4 A0 = a4[0], A1 = a4[1], A2 = a4[2], A3 = a4[3];
    accJ[0]  = fmaf(p, A0.x, accJ[0]);  accJ[1]  = fmaf(p, A0.y, accJ[1]);
    accJ[2]  = fmaf(p, A0.z, accJ[2]);  accJ[3]  = fmaf(p, A0.w, accJ[3]);
    accJ[4]  = fmaf(p, A1.x, accJ[4]);  accJ[5]  = fmaf(p, A1.y, accJ[5]);
    accJ[6]  = fmaf(p, A1.z, accJ[6]);  accJ[7]  = fmaf(p, A1.w, accJ[7]);
    accJ[8]  = fmaf(p, A2.x, accJ[8]);  accJ[9]  = fmaf(p, A2.y, accJ[9]);
    accJ[10] = fmaf(p, A2.z, accJ[10]); accJ[11] = fmaf(p, A2.w, accJ[11]);
    accJ[12] = fmaf(p, A3.x, accJ[12]); accJ[13] = fmaf(p, A3.y, accJ[13]);
    accJ[14] = fmaf(p, A3.z, accJ[14]); accJ[15] = fmaf(p, A3.w, accJ[15]);
  }
  bf16x8 u0, u1;
#pragma unroll
  for (int c = 0; c < 8; ++c) { u0[c] = (__bf16)accJ[c]; u1[c] = (__bf16)accJ[8 + c]; }
  __bf16* wp = W2 + ((size_t)b * CC + co0 + col) * CC + h * 64 + jg * 16;
  *(bf16x8*)(wp)     = u0;
  *(bf16x8*)(wp + 8) = u1;
}

// ---------------------------------------------------------------------------
// Kernel 4: per-batch GEMM  out[b,n,co] = sum_c' vb[b,n,c'] * W2[b,co,c'] + pb[co]
// m97 recipe; XCD-aware 1-D swizzle.
// ---------------------------------------------------------------------------
__global__ __launch_bounds__(256) void k4_gemm(const __bf16* __restrict__ vb,
                                               const __bf16* __restrict__ W2,
                                               const float* __restrict__ pb,
                                               float* __restrict__ out) {
  int id = blockIdx.x;
  const int bz = id / 192;
  const int rem = id - bz * 192;
  const int mg = rem / 48;
  const int idx = rem - mg * 48;
  const int nt = idx >> 3;
  const int mt = mg * 8 + (idx & 7);
  const int m0 = mt * 128, co0 = nt * 128;

  __shared__ __bf16 At[128][32];
  __shared__ __bf16 Bt[128][32];

  const int tid  = threadIdx.x;
  const int w    = tid >> 6, lane = tid & 63;
  const int wm   = w >> 1,   wn   = w & 1;
  const int fr   = lane & 15;
  const int fk   = lane >> 4;

  f32x4 acc[4][4];
#pragma unroll
  for (int tm = 0; tm < 4; ++tm)
#pragma unroll
    for (int tn = 0; tn < 4; ++tn) acc[tm][tn] = (f32x4){0.f, 0.f, 0.f, 0.f};

  const int srow = lane >> 2;
  const int scol = (lane & 3) * 8;
  const __bf16* Ag = vb + (size_t)(bz * NN + m0 + w * 32 + srow) * CC + scol;
  const __bf16* Bg = W2 + ((size_t)bz * CC + co0 + w * 32 + srow) * CC + scol;
  __bf16* lA0 = &At[w * 32][0];
  __bf16* lA1 = &At[w * 32 + 16][0];
  __bf16* lB0 = &Bt[w * 32][0];
  __bf16* lB1 = &Bt[w * 32 + 16][0];

  for (int kk = 0; kk < 24; ++kk) {
    const int kb = kk * 32;
    __syncthreads();
    gload16(Ag + kb,            lA0);
    gload16(Ag + 16 * CC + kb,  lA1);
    gload16(Bg + kb,            lB0);
    gload16(Bg + 16 * CC + kb,  lB1);
    __syncthreads();
    bf16x8 afr[4], bfr[4];
#pragma unroll
    for (int tm = 0; tm < 4; ++tm)
      afr[tm] = *(const bf16x8*)&At[wm * 64 + tm * 16 + fr][fk * 8];
#pragma unroll
    for (int tn = 0; tn < 4; ++tn)
      bfr[tn] = *(const bf16x8*)&Bt[wn * 64 + tn * 16 + fr][fk * 8];
#pragma unroll
    for (int tm = 0; tm < 4; ++tm)
#pragma unroll
      for (int tn = 0; tn < 4; ++tn)
        acc[tm][tn] = __builtin_amdgcn_mfma_f32_16x16x32_bf16(afr[tm], bfr[tn],
                                                              acc[tm][tn], 0, 0, 0);
  }

#pragma unroll
  for (int tn = 0; tn < 4; ++tn) {
    const int co = co0 + wn * 64 + tn * 16 + fr;
    const float bias = pb[co];
#pragma unroll
    for (int tm = 0; tm < 4; ++tm) {
#pragma unroll
      for (int rr = 0; rr < 4; ++rr) {
        const int row = m0 + wm * 64 + tm * 16 + fk * 4 + rr;
        out[(size_t)(bz * NN + row) * CC + co] = acc[tm][tn][rr] + bias;
      }
    }
  }
}

// ---------------------------------------------------------------------------
extern "C" void kernel_launch(void* const* d_in, const int* in_sizes, int n_in,
                              void* d_out, int out_size, void* d_ws, size_t ws_size,
                              hipStream_t stream) {
  const float* x    = (const float*)d_in[0];
  const float* temp = (const float*)d_in[1];
  const float* pw   = (const float*)d_in[2];
  const float* pb   = (const float*)d_in[3];
  float* out = (float*)d_out;
  char* ws = (char*)d_ws;

  // ws layout (bytes) — every buffer fully overwritten each call, no memset:
  //   Spart @ 0        : 8*96*4096*4 = 12,582,912
  //   Qpart @ 12582912 : 8*96*64*4   = 196,608
  //   attn  @ 12779520 : 1,572,864
  //   W2    @ 14352384 : 9,437,184
  //   vb    @ 23789568 : 50,331,648   (total ~74 MB)
  float*  Spart = (float*)(ws);
  float*  Qpart = (float*)(ws + 12582912);
  float*  attn  = (float*)(ws + 12779520);
  __bf16* W2    = (__bf16*)(ws + 14352384);
  __bf16* vb    = (__bf16*)(ws + 23789568);

  hipLaunchKernelGGL(k0_vcvt,    dim3(24576),    dim3(256), 0, stream, x, vb);
  hipLaunchKernelGGL(k1_logits,  dim3(8, 12, 8), dim3(256), 0, stream, x, Spart, Qpart);
  hipLaunchKernelGGL(k2_softmax, dim3(12, 8),    dim3(64),  0, stream, Spart, Qpart, temp, attn);
  hipLaunchKernelGGL(k3_w2,      dim3(12, 12, 8), dim3(256), 0, stream, attn, pw, W2);
  hipLaunchKernelGGL(k4_gemm,    dim3(1536),     dim3(256), 0, stream, vb, W2, pb, out);
}